// Round 1
// baseline (212.934 us; speedup 1.0000x reference)
//
#include <hip/hip_runtime.h>
#include <cmath>

#define SEQ   168
#define NF    8
#define PRED  24
#define CTXN  32
#define HID   8
#define NLAG  11
#define NCOL  640           // 8 features * 80 cols (24 trend + 24 seasonal + 32 ctx), col = j*8+f
#define TB    8             // batch rows per block
#define PI_F  3.14159265358979323846f

// ---------------- workspace layout (floats) ----------------
// [0,200)        dw        softmaxed decomp weights 8x25
// [256,352)      rotc      precomputed Rot-gate coeffs 3 vqc * 2 layers * 4 q * 4
// [1024,1024+168*640)  Wt  composed weights, layout [s][col], col=j*8+f
#define WS_DW    0
#define WS_ROTC  256
#define WS_WT    1024

// ---------------- kernel 0: softmax of decomp weights ----------------
__global__ void k_softmax(const float* __restrict__ decomp_w, float* __restrict__ dw) {
    int f = threadIdx.x;
    if (f >= NF) return;
    const float* row = decomp_w + f * 25;
    float m = row[0];
    for (int k = 1; k < 25; ++k) m = fmaxf(m, row[k]);
    float e[25]; float sum = 0.f;
    for (int k = 0; k < 25; ++k) { e[k] = expf(row[k] - m); sum += e[k]; }
    float inv = 1.f / sum;
    float* o = dw + f * 25;
    for (int k = 0; k < 25; ++k) o[k] = e[k] * inv;
}

// ---------------- kernel 0b: precompute Rot gate coefficients ----------------
// For gate Rot(phi,theta,omega): U = [[ep*c, -em*s],[conj(em)*s, conj(ep)*c]]
// ep = exp(-0.5i(phi+om)), em = exp(0.5i(phi-om)); store A=Re(ep)*c, B=Im(ep)*c,
// C=Re(em)*s, D=Im(em)*s.
__global__ void k_rotpre(const float* __restrict__ vr, const float* __restrict__ vu,
                         const float* __restrict__ vc, float* __restrict__ rotc) {
    int n = threadIdx.x;
    if (n >= 24) return;
    int v = n / 8, rest = n % 8;               // rest = layer*4 + q
    const float* w = (v == 0 ? vr : (v == 1 ? vu : vc)) + rest * 3;
    float phi = w[0], th = w[1], om = w[2];
    float c = cosf(0.5f * th), s = sinf(0.5f * th);
    float ap = -0.5f * (phi + om);
    float am =  0.5f * (phi - om);
    float* o = rotc + n * 4;
    o[0] = cosf(ap) * c;
    o[1] = sinf(ap) * c;
    o[2] = cosf(am) * s;
    o[3] = sinf(am) * s;
}

// ---------------- kernel 1: compose conv into projection weights ----------------
// trend[s'] = sum_k dw[k] * x[clamp(s'+k-12,0,167)]   (edge-padded moving average)
// W_trend[p,sx]    = sum over (s,k): clamp(s+k-12)==sx of trend_w[p,s]*dw[k]
// W_seasonal[p,sx] = seasonal_w[p,sx] - (same composite with seasonal_w)
// W_ctx[c,sx]      = ta_w[c,sx]      - (same composite with ta_w)
__global__ void k_compose(const float* __restrict__ dw,
                          const float* __restrict__ trend_w,
                          const float* __restrict__ seasonal_w,
                          const float* __restrict__ ta_w,
                          float* __restrict__ Wt) {
    int n = blockIdx.x * 256 + threadIdx.x;
    if (n >= SEQ * NCOL) return;
    int sx  = n / NCOL;
    int col = n % NCOL;
    int j = col >> 3;
    int f = col & 7;
    const float* dwf = dw + f * 25;
    const float* wsel;
    int isTrend = 0;
    if (j < 24)      { wsel = trend_w    + j        * SEQ; isTrend = 1; }
    else if (j < 48) { wsel = seasonal_w + (j - 24) * SEQ; }
    else             { wsel = ta_w       + (j - 48) * SEQ; }
    float acc = 0.f;
    if (sx == 0) {
        for (int s = 0; s <= 12; ++s) {
            float cw = 0.f;
            for (int k = 0; k <= 12 - s; ++k) cw += dwf[k];
            acc = fmaf(cw, wsel[s], acc);
        }
    } else if (sx == 167) {
        for (int s = 155; s < 168; ++s) {
            float cw = 0.f;
            for (int k = 179 - s; k < 25; ++k) cw += dwf[k];
            acc = fmaf(cw, wsel[s], acc);
        }
    } else {
        int lo = sx - 12; if (lo < 0) lo = 0;
        int hi = sx + 12; if (hi > 167) hi = 167;
        for (int s = lo; s <= hi; ++s) acc = fmaf(dwf[sx - s + 12], wsel[s], acc);
    }
    Wt[sx * NCOL + col] = isTrend ? acc : (wsel[sx] - acc);
}

// ---------------- VQC: 16 lanes hold the 16 complex amplitudes ----------------
__device__ __forceinline__ float shflg(float v, int grp, int idx) {
    return __shfl(v, grp + idx, 64);
}

// qubit q <-> bit (3-q); lane l = amplitude index; grp = 16-lane group base in wave
__device__ void vqc_run(const float cq[4], const float sq[4],
                        const float* __restrict__ rc,   // 2 layers * 4 q * 4 floats
                        int l, int grp, float exps[4]) {
    float re = (l == 0) ? 1.f : 0.f;
    float im = 0.f;
    #pragma unroll
    for (int layer = 0; layer < 2; ++layer) {
        // RY(inputs[q]) on each qubit
        #pragma unroll
        for (int q = 0; q < 4; ++q) {
            int m = 1 << (3 - q);
            float pre = shflg(re, grp, l ^ m);
            float pim = shflg(im, grp, l ^ m);
            float sg = (l & m) ? sq[q] : -sq[q];
            re = cq[q] * re + sg * pre;
            im = cq[q] * im + sg * pim;
        }
        // Rot(weights[layer,q]) on each qubit
        #pragma unroll
        for (int q = 0; q < 4; ++q) {
            int m = 1 << (3 - q);
            const float* g = rc + (layer * 4 + q) * 4;
            float A = g[0], B = g[1], C = g[2], D = g[3];
            float pre = shflg(re, grp, l ^ m);
            float pim = shflg(im, grp, l ^ m);
            float car, cai, cpr, cpi;
            if (l & m) { car = A; cai = -B; cpr =  C; cpi = -D; }   // conj(ep)*c, conj(em)*s
            else       { car = A; cai =  B; cpr = -C; cpi = -D; }   // ep*c, -em*s
            float nre = car * re - cai * im + cpr * pre - cpi * pim;
            float nim = car * im + cai * re + cpr * pim + cpi * pre;
            re = nre; im = nim;
        }
        // CNOT ring q -> (q+1)%4
        #pragma unroll
        for (int q = 0; q < 4; ++q) {
            int mc = 1 << (3 - q);
            int mt = 1 << (3 - ((q + 1) & 3));
            float pre = shflg(re, grp, l ^ mt);
            float pim = shflg(im, grp, l ^ mt);
            if (l & mc) { re = pre; im = pim; }
        }
    }
    float prob = re * re + im * im;
    float v0 = (l & 8) ? -prob : prob;
    float v1 = (l & 4) ? -prob : prob;
    float v2 = (l & 2) ? -prob : prob;
    float v3 = (l & 1) ? -prob : prob;
    #pragma unroll
    for (int m = 1; m < 16; m <<= 1) {
        v0 += __shfl_xor(v0, m, 64);
        v1 += __shfl_xor(v1, m, 64);
        v2 += __shfl_xor(v2, m, 64);
        v3 += __shfl_xor(v3, m, 64);
    }
    exps[0] = v0; exps[1] = v1; exps[2] = v2; exps[3] = v3;
}

__device__ __forceinline__ float sigm(float x) { return 1.f / (1.f + expf(-x)); }

// ---------------- main fused kernel ----------------
__global__ __launch_bounds__(256, 2)
void k_main(const float* __restrict__ x, const float* __restrict__ Wt,
            const float* __restrict__ rotc,
            const float* __restrict__ trend_b, const float* __restrict__ seasonal_b,
            const float* __restrict__ h0_w, const float* __restrict__ h0_b,
            const float* __restrict__ ta_b,
            const float* __restrict__ sc_w, const float* __restrict__ sc_b,
            const float* __restrict__ crz_w, const float* __restrict__ crz_b,
            const float* __restrict__ cn_w, const float* __restrict__ cn_b,
            const float* __restrict__ expand_w, const float* __restrict__ expand_b,
            const float* __restrict__ mod_w, const float* __restrict__ mod_b,
            const float* __restrict__ fusion_alpha,
            float* __restrict__ out, int Btot)
{
    __shared__ float xt[SEQ * NF * TB];   // [s*8+f][r]
    __shared__ float ytile[TB * NCOL];    // [r][col], col=j*8+f
    __shared__ float scw[HID * 256];
    __shared__ float modt[TB * PRED];

    const int t  = threadIdx.x;
    const int b0 = blockIdx.x * TB;
    const float* xb = x + (size_t)b0 * (SEQ * NF);

    // stage x tile (transposed: row index innermost) + sc_w
    for (int e = t; e < TB * SEQ * NF; e += 256) {
        int r  = e / (SEQ * NF);
        int sf = e % (SEQ * NF);
        float v = (b0 + r < Btot) ? xb[e] : 0.f;
        xt[sf * TB + r] = v;
    }
    for (int e = t; e < HID * 256; e += 256) scw[e] = sc_w[e];
    __syncthreads();

    // ---- Phase A: y[r][col] = sum_s x[r,s,f] * W[s][col]  (col = j*8+f) ----
    {
        const int c  = t & 63;       // column lane: f = c&7, jj = c>>3
        const int rg = t >> 6;       // row group: rows rg*2, rg*2+1
        const int f  = c & 7;
        float acc[10][2];
        #pragma unroll
        for (int i = 0; i < 10; ++i) { acc[i][0] = 0.f; acc[i][1] = 0.f; }
        for (int s = 0; s < SEQ; ++s) {
            const float2 xv = *(const float2*)&xt[(s * NF + f) * TB + rg * 2];
            const float* wr = Wt + s * NCOL + c;
            #pragma unroll
            for (int i = 0; i < 10; ++i) {
                float w = wr[i * 64];                       // coalesced: lane-consecutive
                acc[i][0] = fmaf(w, xv.x, acc[i][0]);
                acc[i][1] = fmaf(w, xv.y, acc[i][1]);
            }
        }
        #pragma unroll
        for (int i = 0; i < 10; ++i) {
            ytile[(rg * 2 + 0) * NCOL + c + 64 * i] = acc[i][0];
            ytile[(rg * 2 + 1) * NCOL + c + 64 * i] = acc[i][1];
        }
    }
    __syncthreads();

    // ---- Phase B: per-row scalar chain, 16 lanes per row (waves 0-1) ----
    if (t < 128) {
        const int wv   = t >> 6;
        const int lane = t & 63;
        const int l    = lane & 15;
        const int grp  = lane & 48;
        const int r    = wv * 4 + (lane >> 4);

        // lags (feature 7) -> h0, computed redundantly per lane
        const int LIDX[NLAG] = {167,166,165,164,163,162,145,144,143,1,0};
        float lag[NLAG];
        #pragma unroll
        for (int i = 0; i < NLAG; ++i) lag[i] = xt[(LIDX[i] * NF + 7) * TB + r];
        float h0v[HID];
        #pragma unroll
        for (int h = 0; h < HID; ++h) {
            float a = h0_b[h];
            #pragma unroll
            for (int i = 0; i < NLAG; ++i) a = fmaf(lag[i], h0_w[h * NLAG + i], a);
            h0v[h] = tanhf(a);
        }

        // gru_in: ctx flat (f*32+c) dot sc_w, distributed over 16 lanes
        float ga[HID];
        #pragma unroll
        for (int h = 0; h < HID; ++h) ga[h] = 0.f;
        for (int k = 0; k < 16; ++k) {
            int fc = l * 16 + k;
            int ff = fc >> 5, cc = fc & 31;
            float yv = ytile[r * NCOL + 384 + cc * 8 + ff] + ta_b[cc];
            #pragma unroll
            for (int h = 0; h < HID; ++h) ga[h] = fmaf(yv, scw[h * 256 + fc], ga[h]);
        }
        #pragma unroll
        for (int m = 1; m < 16; m <<= 1) {
            #pragma unroll
            for (int h = 0; h < HID; ++h) ga[h] += __shfl_xor(ga[h], m, 64);
        }
        float gin[HID];
        #pragma unroll
        for (int h = 0; h < HID; ++h) gin[h] = tanhf(ga[h] + sc_b[h]);

        // rz_in = tanh([gin, h0] @ crz_w.T + b) * pi
        float rz[4];
        #pragma unroll
        for (int q = 0; q < 4; ++q) {
            float a = crz_b[q];
            #pragma unroll
            for (int k = 0; k < 8; ++k) a = fmaf(gin[k], crz_w[q * 16 + k], a);
            #pragma unroll
            for (int k = 0; k < 8; ++k) a = fmaf(h0v[k], crz_w[q * 16 + 8 + k], a);
            rz[q] = tanhf(a) * PI_F;
        }
        float cq[4], sq[4];
        #pragma unroll
        for (int q = 0; q < 4; ++q) { cq[q] = cosf(0.5f * rz[q]); sq[q] = sinf(0.5f * rz[q]); }

        float er[4], ez[4];
        vqc_run(cq, sq, rotc + 0 * 32, l, grp, er);
        vqc_run(cq, sq, rotc + 1 * 32, l, grp, ez);

        float rr[HID], zz[HID];
        #pragma unroll
        for (int h = 0; h < HID; ++h) {
            float a = expand_b[h], b = expand_b[h];
            #pragma unroll
            for (int q = 0; q < 4; ++q) {
                a = fmaf(er[q], expand_w[h * 4 + q], a);
                b = fmaf(ez[q], expand_w[h * 4 + q], b);
            }
            rr[h] = sigm(a);
            zz[h] = sigm(b);
        }

        float ni[4];
        #pragma unroll
        for (int q = 0; q < 4; ++q) {
            float a = cn_b[q];
            #pragma unroll
            for (int k = 0; k < 8; ++k) a = fmaf(rr[k] * h0v[k], cn_w[q * 16 + k], a);
            #pragma unroll
            for (int k = 0; k < 8; ++k) a = fmaf(gin[k], cn_w[q * 16 + 8 + k], a);
            ni[q] = tanhf(a) * PI_F;
        }
        #pragma unroll
        for (int q = 0; q < 4; ++q) { cq[q] = cosf(0.5f * ni[q]); sq[q] = sinf(0.5f * ni[q]); }
        float en[4];
        vqc_run(cq, sq, rotc + 2 * 32, l, grp, en);

        float hn[HID];
        #pragma unroll
        for (int h = 0; h < HID; ++h) {
            float a = expand_b[h];
            #pragma unroll
            for (int q = 0; q < 4; ++q) a = fmaf(en[q], expand_w[h * 4 + q], a);
            float nn = tanhf(a);
            hn[h] = (1.f - zz[h]) * nn + zz[h] * h0v[h];
        }

        // modulation -> LDS
        {
            int p = l;
            float a = mod_b[p];
            #pragma unroll
            for (int h = 0; h < HID; ++h) a = fmaf(hn[h], mod_w[p * 8 + h], a);
            modt[r * PRED + p] = tanhf(a);
            if (l < 8) {
                p = l + 16;
                a = mod_b[p];
                #pragma unroll
                for (int h = 0; h < HID; ++h) a = fmaf(hn[h], mod_w[p * 8 + h], a);
                modt[r * PRED + p] = tanhf(a);
            }
        }
    }
    __syncthreads();

    // ---- epilogue: fuse and store ----
    const float alpha = 1.f / (1.f + expf(-fusion_alpha[0]));
    for (int e = t; e < TB * PRED * NF; e += 256) {
        int r  = e / (PRED * NF);
        if (b0 + r >= Btot) break;
        int pf = e % (PRED * NF);
        int p  = pf >> 3;
        float tv = ytile[r * NCOL + pf]       + trend_b[p];
        float sv = ytile[r * NCOL + 192 + pf] + seasonal_b[p];
        float md = modt[r * PRED + p];
        out[(size_t)(b0 + r) * (PRED * NF) + pf] = alpha * (sv * (1.f + md)) + (1.f - alpha) * tv;
    }
}

extern "C" void kernel_launch(void* const* d_in, const int* in_sizes, int n_in,
                              void* d_out, int out_size, void* d_ws, size_t ws_size,
                              hipStream_t stream) {
    const float* x          = (const float*)d_in[0];
    const float* decomp_w   = (const float*)d_in[1];
    const float* trend_w    = (const float*)d_in[2];
    const float* trend_b    = (const float*)d_in[3];
    const float* seasonal_w = (const float*)d_in[4];
    const float* seasonal_b = (const float*)d_in[5];
    const float* h0_w       = (const float*)d_in[6];
    const float* h0_b       = (const float*)d_in[7];
    const float* ta_w       = (const float*)d_in[8];
    const float* ta_b       = (const float*)d_in[9];
    const float* sc_w       = (const float*)d_in[10];
    const float* sc_b       = (const float*)d_in[11];
    const float* crz_w      = (const float*)d_in[12];
    const float* crz_b      = (const float*)d_in[13];
    const float* cn_w       = (const float*)d_in[14];
    const float* cn_b       = (const float*)d_in[15];
    const float* vqc_r      = (const float*)d_in[16];
    const float* vqc_u      = (const float*)d_in[17];
    const float* vqc_c      = (const float*)d_in[18];
    const float* expand_w   = (const float*)d_in[19];
    const float* expand_b   = (const float*)d_in[20];
    const float* mod_w      = (const float*)d_in[21];
    const float* mod_b      = (const float*)d_in[22];
    const float* fus_a      = (const float*)d_in[23];
    float* out = (float*)d_out;

    float* ws   = (float*)d_ws;
    float* dw   = ws + WS_DW;
    float* rotc = ws + WS_ROTC;
    float* Wt   = ws + WS_WT;

    const int Btot = in_sizes[0] / (SEQ * NF);

    k_softmax<<<1, 64, 0, stream>>>(decomp_w, dw);
    k_rotpre<<<1, 64, 0, stream>>>(vqc_r, vqc_u, vqc_c, rotc);
    k_compose<<<(SEQ * NCOL + 255) / 256, 256, 0, stream>>>(dw, trend_w, seasonal_w, ta_w, Wt);

    const int nblk = (Btot + TB - 1) / TB;
    k_main<<<nblk, 256, 0, stream>>>(x, Wt, rotc,
                                     trend_b, seasonal_b, h0_w, h0_b, ta_b,
                                     sc_w, sc_b, crz_w, crz_b, cn_w, cn_b,
                                     expand_w, expand_b, mod_w, mod_b,
                                     fus_a, out, Btot);
}

// Round 2
// 168.577 us; speedup vs baseline: 1.2631x; 1.2631x over previous
//
#include <hip/hip_runtime.h>
#include <cmath>

#define SEQ   168
#define NF    8
#define PRED  24
#define CTXN  32
#define HID   8
#define NLAG  11
#define NCOL  640           // 8 features * 80 cols (24 trend + 24 seasonal + 32 ctx), col = j*8+f
#define TB    8             // batch rows per block
#define PI_F  3.14159265358979323846f

// ---------------- workspace layout (floats) ----------------
#define WS_DW    0
#define WS_ROTC  256
#define WS_WT    1024

// ---------------- fast math ----------------
__device__ __forceinline__ float fexp(float x)  { return __expf(x); }
__device__ __forceinline__ float frcp(float x)  { return __builtin_amdgcn_rcpf(x); }
__device__ __forceinline__ float ftanh(float x) {
    float xc = fminf(fmaxf(x, -15.f), 15.f);
    float e  = __expf(2.f * xc);
    return (e - 1.f) * frcp(e + 1.f);
}
__device__ __forceinline__ float sigm(float x) { return frcp(1.f + __expf(-x)); }

// ---------------- kernel 0: softmax of decomp weights ----------------
__global__ void k_softmax(const float* __restrict__ decomp_w, float* __restrict__ dw) {
    int f = threadIdx.x;
    if (f >= NF) return;
    const float* row = decomp_w + f * 25;
    float m = row[0];
    for (int k = 1; k < 25; ++k) m = fmaxf(m, row[k]);
    float e[25]; float sum = 0.f;
    for (int k = 0; k < 25; ++k) { e[k] = expf(row[k] - m); sum += e[k]; }
    float inv = 1.f / sum;
    float* o = dw + f * 25;
    for (int k = 0; k < 25; ++k) o[k] = e[k] * inv;
}

// ---------------- kernel 0b: precompute Rot gate coefficients ----------------
__global__ void k_rotpre(const float* __restrict__ vr, const float* __restrict__ vu,
                         const float* __restrict__ vc, float* __restrict__ rotc) {
    int n = threadIdx.x;
    if (n >= 24) return;
    int v = n / 8, rest = n % 8;               // rest = layer*4 + q
    const float* w = (v == 0 ? vr : (v == 1 ? vu : vc)) + rest * 3;
    float phi = w[0], th = w[1], om = w[2];
    float c = cosf(0.5f * th), s = sinf(0.5f * th);
    float ap = -0.5f * (phi + om);
    float am =  0.5f * (phi - om);
    float* o = rotc + n * 4;
    o[0] = cosf(ap) * c;
    o[1] = sinf(ap) * c;
    o[2] = cosf(am) * s;
    o[3] = sinf(am) * s;
}

// ---------------- kernel 1: compose conv into projection weights ----------------
__global__ void k_compose(const float* __restrict__ dw,
                          const float* __restrict__ trend_w,
                          const float* __restrict__ seasonal_w,
                          const float* __restrict__ ta_w,
                          float* __restrict__ Wt) {
    int n = blockIdx.x * 256 + threadIdx.x;
    if (n >= SEQ * NCOL) return;
    int sx  = n / NCOL;
    int col = n % NCOL;
    int j = col >> 3;
    int f = col & 7;
    const float* dwf = dw + f * 25;
    const float* wsel;
    int isTrend = 0;
    if (j < 24)      { wsel = trend_w    + j        * SEQ; isTrend = 1; }
    else if (j < 48) { wsel = seasonal_w + (j - 24) * SEQ; }
    else             { wsel = ta_w       + (j - 48) * SEQ; }
    float acc = 0.f;
    if (sx == 0) {
        for (int s = 0; s <= 12; ++s) {
            float cw = 0.f;
            for (int k = 0; k <= 12 - s; ++k) cw += dwf[k];
            acc = fmaf(cw, wsel[s], acc);
        }
    } else if (sx == 167) {
        for (int s = 155; s < 168; ++s) {
            float cw = 0.f;
            for (int k = 179 - s; k < 25; ++k) cw += dwf[k];
            acc = fmaf(cw, wsel[s], acc);
        }
    } else {
        int lo = sx - 12; if (lo < 0) lo = 0;
        int hi = sx + 12; if (hi > 167) hi = 167;
        for (int s = lo; s <= hi; ++s) acc = fmaf(dwf[sx - s + 12], wsel[s], acc);
    }
    Wt[sx * NCOL + col] = isTrend ? acc : (wsel[sx] - acc);
}

// ---------------- VQC: 16 lanes hold the 16 complex amplitudes ----------------
__device__ __forceinline__ float shflg(float v, int grp, int idx) {
    return __shfl(v, grp + idx, 64);
}

__device__ void vqc_run(const float cq[4], const float sq[4],
                        const float* __restrict__ rc,   // 2 layers * 4 q * 4 floats
                        int l, int grp, float exps[4]) {
    float re = (l == 0) ? 1.f : 0.f;
    float im = 0.f;
    #pragma unroll
    for (int layer = 0; layer < 2; ++layer) {
        #pragma unroll
        for (int q = 0; q < 4; ++q) {
            int m = 1 << (3 - q);
            float pre = shflg(re, grp, l ^ m);
            float pim = shflg(im, grp, l ^ m);
            float sg = (l & m) ? sq[q] : -sq[q];
            re = cq[q] * re + sg * pre;
            im = cq[q] * im + sg * pim;
        }
        #pragma unroll
        for (int q = 0; q < 4; ++q) {
            int m = 1 << (3 - q);
            const float* g = rc + (layer * 4 + q) * 4;
            float A = g[0], B = g[1], C = g[2], D = g[3];
            float pre = shflg(re, grp, l ^ m);
            float pim = shflg(im, grp, l ^ m);
            float car, cai, cpr, cpi;
            if (l & m) { car = A; cai = -B; cpr =  C; cpi = -D; }
            else       { car = A; cai =  B; cpr = -C; cpi = -D; }
            float nre = car * re - cai * im + cpr * pre - cpi * pim;
            float nim = car * im + cai * re + cpr * pim + cpi * pre;
            re = nre; im = nim;
        }
        #pragma unroll
        for (int q = 0; q < 4; ++q) {
            int mc = 1 << (3 - q);
            int mt = 1 << (3 - ((q + 1) & 3));
            float pre = shflg(re, grp, l ^ mt);
            float pim = shflg(im, grp, l ^ mt);
            if (l & mc) { re = pre; im = pim; }
        }
    }
    float prob = re * re + im * im;
    float v0 = (l & 8) ? -prob : prob;
    float v1 = (l & 4) ? -prob : prob;
    float v2 = (l & 2) ? -prob : prob;
    float v3 = (l & 1) ? -prob : prob;
    #pragma unroll
    for (int m = 1; m < 16; m <<= 1) {
        v0 += __shfl_xor(v0, m, 64);
        v1 += __shfl_xor(v1, m, 64);
        v2 += __shfl_xor(v2, m, 64);
        v3 += __shfl_xor(v3, m, 64);
    }
    exps[0] = v0; exps[1] = v1; exps[2] = v2; exps[3] = v3;
}

// ---------------- main fused kernel ----------------
__global__ __launch_bounds__(256, 6)
void k_main(const float* __restrict__ x, const float* __restrict__ Wt,
            const float* __restrict__ rotc,
            const float* __restrict__ trend_b, const float* __restrict__ seasonal_b,
            const float* __restrict__ h0_w, const float* __restrict__ h0_b,
            const float* __restrict__ ta_b,
            const float* __restrict__ sc_w, const float* __restrict__ sc_b,
            const float* __restrict__ crz_w, const float* __restrict__ crz_b,
            const float* __restrict__ cn_w, const float* __restrict__ cn_b,
            const float* __restrict__ expand_w, const float* __restrict__ expand_b,
            const float* __restrict__ mod_w, const float* __restrict__ mod_b,
            const float* __restrict__ fusion_alpha,
            float* __restrict__ out, int Btot)
{
    __shared__ float ytile[TB * NCOL];    // [r][col], col=j*8+f
    __shared__ float modt[TB * PRED];

    const int t  = threadIdx.x;
    const int b0 = blockIdx.x * TB;

    // ---- Phase A: y[r][col] = sum_s x[r,s,f] * W[s][col]  (col = j*8+f) ----
    {
        const int c  = t & 63;       // column lane: f = c&7, jj = c>>3
        const int rg = t >> 6;       // row group: rows rg*2, rg*2+1
        const int f  = c & 7;
        int row0 = b0 + rg * 2;     if (row0 > Btot - 1) row0 = Btot - 1;
        int row1 = b0 + rg * 2 + 1; if (row1 > Btot - 1) row1 = Btot - 1;
        const float* xr0 = x + (size_t)row0 * (SEQ * NF) + f;
        const float* xr1 = x + (size_t)row1 * (SEQ * NF) + f;
        float acc[10][2];
        #pragma unroll
        for (int i = 0; i < 10; ++i) { acc[i][0] = 0.f; acc[i][1] = 0.f; }
        const float* wr = Wt + c;
        #pragma unroll 2
        for (int s = 0; s < SEQ; ++s) {
            float x0 = xr0[s * NF];
            float x1 = xr1[s * NF];
            #pragma unroll
            for (int i = 0; i < 10; ++i) {
                float w = wr[i * 64];                       // lane-consecutive, L2-served
                acc[i][0] = fmaf(w, x0, acc[i][0]);
                acc[i][1] = fmaf(w, x1, acc[i][1]);
            }
            wr += NCOL;
        }
        #pragma unroll
        for (int i = 0; i < 10; ++i) {
            ytile[(rg * 2 + 0) * NCOL + c + 64 * i] = acc[i][0];
            ytile[(rg * 2 + 1) * NCOL + c + 64 * i] = acc[i][1];
        }
    }
    __syncthreads();

    // ---- Phase B: per-row scalar chain, 16 lanes per row (waves 0-1) ----
    if (t < 128) {
        const int wv   = t >> 6;
        const int lane = t & 63;
        const int l    = lane & 15;
        const int grp  = lane & 48;
        const int r    = wv * 4 + (lane >> 4);
        int rowg = b0 + r; if (rowg > Btot - 1) rowg = Btot - 1;
        const float* xrow = x + (size_t)rowg * (SEQ * NF);

        // lags (feature 7) -> h0
        const int LIDX[NLAG] = {167,166,165,164,163,162,145,144,143,1,0};
        float lag[NLAG];
        #pragma unroll
        for (int i = 0; i < NLAG; ++i) lag[i] = xrow[LIDX[i] * NF + 7];
        float h0v[HID];
        #pragma unroll
        for (int h = 0; h < HID; ++h) {
            float a = h0_b[h];
            #pragma unroll
            for (int i = 0; i < NLAG; ++i) a = fmaf(lag[i], h0_w[h * NLAG + i], a);
            h0v[h] = ftanh(a);
        }

        // gru_in: ctx flat (f*32+c) dot sc_w, distributed over 16 lanes
        float ga[HID];
        #pragma unroll
        for (int h = 0; h < HID; ++h) ga[h] = 0.f;
        for (int k = 0; k < 16; ++k) {
            int fc = l * 16 + k;
            int ff = fc >> 5, cc = fc & 31;
            float yv = ytile[r * NCOL + 384 + cc * 8 + ff] + ta_b[cc];
            #pragma unroll
            for (int h = 0; h < HID; ++h) ga[h] = fmaf(yv, sc_w[h * 256 + fc], ga[h]);
        }
        #pragma unroll
        for (int m = 1; m < 16; m <<= 1) {
            #pragma unroll
            for (int h = 0; h < HID; ++h) ga[h] += __shfl_xor(ga[h], m, 64);
        }
        float gin[HID];
        #pragma unroll
        for (int h = 0; h < HID; ++h) gin[h] = ftanh(ga[h] + sc_b[h]);

        // rz_in = tanh([gin, h0] @ crz_w.T + b) * pi
        float rz[4];
        #pragma unroll
        for (int q = 0; q < 4; ++q) {
            float a = crz_b[q];
            #pragma unroll
            for (int k = 0; k < 8; ++k) a = fmaf(gin[k], crz_w[q * 16 + k], a);
            #pragma unroll
            for (int k = 0; k < 8; ++k) a = fmaf(h0v[k], crz_w[q * 16 + 8 + k], a);
            rz[q] = ftanh(a) * PI_F;
        }
        float cq[4], sq[4];
        #pragma unroll
        for (int q = 0; q < 4; ++q) { cq[q] = __cosf(0.5f * rz[q]); sq[q] = __sinf(0.5f * rz[q]); }

        float er[4], ez[4];
        vqc_run(cq, sq, rotc + 0 * 32, l, grp, er);
        vqc_run(cq, sq, rotc + 1 * 32, l, grp, ez);

        float rr[HID], zz[HID];
        #pragma unroll
        for (int h = 0; h < HID; ++h) {
            float a = expand_b[h], b = expand_b[h];
            #pragma unroll
            for (int q = 0; q < 4; ++q) {
                a = fmaf(er[q], expand_w[h * 4 + q], a);
                b = fmaf(ez[q], expand_w[h * 4 + q], b);
            }
            rr[h] = sigm(a);
            zz[h] = sigm(b);
        }

        float ni[4];
        #pragma unroll
        for (int q = 0; q < 4; ++q) {
            float a = cn_b[q];
            #pragma unroll
            for (int k = 0; k < 8; ++k) a = fmaf(rr[k] * h0v[k], cn_w[q * 16 + k], a);
            #pragma unroll
            for (int k = 0; k < 8; ++k) a = fmaf(gin[k], cn_w[q * 16 + 8 + k], a);
            ni[q] = ftanh(a) * PI_F;
        }
        #pragma unroll
        for (int q = 0; q < 4; ++q) { cq[q] = __cosf(0.5f * ni[q]); sq[q] = __sinf(0.5f * ni[q]); }
        float en[4];
        vqc_run(cq, sq, rotc + 2 * 32, l, grp, en);

        float hn[HID];
        #pragma unroll
        for (int h = 0; h < HID; ++h) {
            float a = expand_b[h];
            #pragma unroll
            for (int q = 0; q < 4; ++q) a = fmaf(en[q], expand_w[h * 4 + q], a);
            float nn = ftanh(a);
            hn[h] = (1.f - zz[h]) * nn + zz[h] * h0v[h];
        }

        // modulation -> LDS
        {
            int p = l;
            float a = mod_b[p];
            #pragma unroll
            for (int h = 0; h < HID; ++h) a = fmaf(hn[h], mod_w[p * 8 + h], a);
            modt[r * PRED + p] = ftanh(a);
            if (l < 8) {
                p = l + 16;
                a = mod_b[p];
                #pragma unroll
                for (int h = 0; h < HID; ++h) a = fmaf(hn[h], mod_w[p * 8 + h], a);
                modt[r * PRED + p] = ftanh(a);
            }
        }
    }
    __syncthreads();

    // ---- epilogue: fuse and store ----
    const float alpha = sigm(fusion_alpha[0]);
    for (int e = t; e < TB * PRED * NF; e += 256) {
        int r  = e / (PRED * NF);
        if (b0 + r >= Btot) break;
        int pf = e % (PRED * NF);
        int p  = pf >> 3;
        float tv = ytile[r * NCOL + pf]       + trend_b[p];
        float sv = ytile[r * NCOL + 192 + pf] + seasonal_b[p];
        float md = modt[r * PRED + p];
        out[(size_t)(b0 + r) * (PRED * NF) + pf] = alpha * (sv * (1.f + md)) + (1.f - alpha) * tv;
    }
}

extern "C" void kernel_launch(void* const* d_in, const int* in_sizes, int n_in,
                              void* d_out, int out_size, void* d_ws, size_t ws_size,
                              hipStream_t stream) {
    const float* x          = (const float*)d_in[0];
    const float* decomp_w   = (const float*)d_in[1];
    const float* trend_w    = (const float*)d_in[2];
    const float* trend_b    = (const float*)d_in[3];
    const float* seasonal_w = (const float*)d_in[4];
    const float* seasonal_b = (const float*)d_in[5];
    const float* h0_w       = (const float*)d_in[6];
    const float* h0_b       = (const float*)d_in[7];
    const float* ta_w       = (const float*)d_in[8];
    const float* ta_b       = (const float*)d_in[9];
    const float* sc_w       = (const float*)d_in[10];
    const float* sc_b       = (const float*)d_in[11];
    const float* crz_w      = (const float*)d_in[12];
    const float* crz_b      = (const float*)d_in[13];
    const float* cn_w       = (const float*)d_in[14];
    const float* cn_b       = (const float*)d_in[15];
    const float* vqc_r      = (const float*)d_in[16];
    const float* vqc_u      = (const float*)d_in[17];
    const float* vqc_c      = (const float*)d_in[18];
    const float* expand_w   = (const float*)d_in[19];
    const float* expand_b   = (const float*)d_in[20];
    const float* mod_w      = (const float*)d_in[21];
    const float* mod_b      = (const float*)d_in[22];
    const float* fus_a      = (const float*)d_in[23];
    float* out = (float*)d_out;

    float* ws   = (float*)d_ws;
    float* dw   = ws + WS_DW;
    float* rotc = ws + WS_ROTC;
    float* Wt   = ws + WS_WT;

    const int Btot = in_sizes[0] / (SEQ * NF);

    k_softmax<<<1, 64, 0, stream>>>(decomp_w, dw);
    k_rotpre<<<1, 64, 0, stream>>>(vqc_r, vqc_u, vqc_c, rotc);
    k_compose<<<(SEQ * NCOL + 255) / 256, 256, 0, stream>>>(dw, trend_w, seasonal_w, ta_w, Wt);

    const int nblk = (Btot + TB - 1) / TB;
    k_main<<<nblk, 256, 0, stream>>>(x, Wt, rotc,
                                     trend_b, seasonal_b, h0_w, h0_b, ta_b,
                                     sc_w, sc_b, crz_w, crz_b, cn_w, cn_b,
                                     expand_w, expand_b, mod_w, mod_b,
                                     fus_a, out, Btot);
}

// Round 3
// 111.633 us; speedup vs baseline: 1.9074x; 1.5101x over previous
//
#include <hip/hip_runtime.h>
#include <hip/hip_bf16.h>
#include <cmath>

#define SEQ   168
#define NF    8
#define PRED  24
#define HID   8
#define KTOT  1344          // SEQ*NF, the GEMM K dim (k = s*8+f == x row flat index)
#define NOUT  400           // 192 trend + 192 seasonal + 8 gin + 8 h0
#define NB    5             // col tiles of 80
#define NCHUNK 21           // 1344/64 k-chunks
#define CHUNKB 10240        // 80 cols * 64 k * 2B, one LDS image chunk
#define PI_F  3.14159265358979323846f

// ---------------- workspace layout ----------------
// floats:
#define WS_DW    0          // 8*25 softmaxed decomp weights
#define WS_ROTC  256        // 3*2*4*4 rot coeffs
#define WS_CGIN  512        // 8 gin constants
#define WS_WT    1024       // 168*640 composed f32 weights (trend/seasonal/ctx), ends 108544
#define WS_WGIN  110592     // 1344*8 gin-folded weights [k][h], ends 121344
#define WS_Y     400000     // 16384*400 f32 GEMM output (byte 1,600,000)
// bytes:
#define WS_IMG_BYTE 524288  // bf16 B image: 5*21*10240 = 1,075,200 bytes (pre-swizzled)

typedef __attribute__((ext_vector_type(8))) short bf16x8;
typedef __attribute__((ext_vector_type(4))) float f32x4;

__device__ __forceinline__ float frcp(float x)  { return __builtin_amdgcn_rcpf(x); }
__device__ __forceinline__ float ftanh(float x) {
    float xc = fminf(fmaxf(x, -15.f), 15.f);
    float e  = __expf(2.f * xc);
    return (e - 1.f) * frcp(e + 1.f);
}
__device__ __forceinline__ float sigm(float x) { return frcp(1.f + __expf(-x)); }
__device__ __forceinline__ unsigned short f2bf(float f) {
    __hip_bfloat16 h = __float2bfloat16(f);
    return __builtin_bit_cast(unsigned short, h);
}

// ---------------- setup: softmax(dw) + rot coeffs + gin consts ----------------
__global__ void k_setup(const float* __restrict__ decomp_w,
                        const float* __restrict__ vr, const float* __restrict__ vu,
                        const float* __restrict__ vc,
                        const float* __restrict__ sc_w, const float* __restrict__ sc_b,
                        const float* __restrict__ ta_b,
                        float* __restrict__ dw, float* __restrict__ rotc,
                        float* __restrict__ cgin) {
    int t = threadIdx.x;
    if (t < 8) {
        const float* row = decomp_w + t * 25;
        float m = row[0];
        for (int k = 1; k < 25; ++k) m = fmaxf(m, row[k]);
        float e[25]; float sum = 0.f;
        for (int k = 0; k < 25; ++k) { e[k] = expf(row[k] - m); sum += e[k]; }
        float inv = 1.f / sum;
        for (int k = 0; k < 25; ++k) dw[t * 25 + k] = e[k] * inv;
    } else if (t >= 64 && t < 88) {
        int n = t - 64;
        int v = n / 8, rest = n % 8;
        const float* w = (v == 0 ? vr : (v == 1 ? vu : vc)) + rest * 3;
        float phi = w[0], th = w[1], om = w[2];
        float c = cosf(0.5f * th), s = sinf(0.5f * th);
        float ap = -0.5f * (phi + om);
        float am =  0.5f * (phi - om);
        float* o = rotc + n * 4;
        o[0] = cosf(ap) * c;
        o[1] = sinf(ap) * c;
        o[2] = cosf(am) * s;
        o[3] = sinf(am) * s;
    } else if (t >= 96 && t < 104) {
        int h = t - 96;
        float a = sc_b[h];
        for (int cc = 0; cc < 32; ++cc) {
            float s = 0.f;
            for (int f = 0; f < 8; ++f) s += sc_w[h * 256 + f * 32 + cc];
            a = fmaf(ta_b[cc], s, a);
        }
        cgin[h] = a;
    }
}

// ---------------- compose conv into projection weights (f32, verified) ----------------
// Wt cols: 0-191 trend (j*8+f), 192-383 seasonal, 384-639 ctx (48+cc)*8+f
__global__ void k_compose(const float* __restrict__ dw,
                          const float* __restrict__ trend_w,
                          const float* __restrict__ seasonal_w,
                          const float* __restrict__ ta_w,
                          float* __restrict__ Wt) {
    int n = blockIdx.x * 256 + threadIdx.x;
    if (n >= SEQ * 640) return;
    int sx  = n / 640;
    int col = n % 640;
    int j = col >> 3;
    int f = col & 7;
    const float* dwf = dw + f * 25;
    const float* wsel;
    int isTrend = 0;
    if (j < 24)      { wsel = trend_w    + j        * SEQ; isTrend = 1; }
    else if (j < 48) { wsel = seasonal_w + (j - 24) * SEQ; }
    else             { wsel = ta_w       + (j - 48) * SEQ; }
    float acc = 0.f;
    if (sx == 0) {
        for (int s = 0; s <= 12; ++s) {
            float cw = 0.f;
            for (int k = 0; k <= 12 - s; ++k) cw += dwf[k];
            acc = fmaf(cw, wsel[s], acc);
        }
    } else if (sx == 167) {
        for (int s = 155; s < 168; ++s) {
            float cw = 0.f;
            for (int k = 179 - s; k < 25; ++k) cw += dwf[k];
            acc = fmaf(cw, wsel[s], acc);
        }
    } else {
        int lo = sx - 12; if (lo < 0) lo = 0;
        int hi = sx + 12; if (hi > 167) hi = 167;
        for (int s = lo; s <= hi; ++s) acc = fmaf(dwf[sx - s + 12], wsel[s], acc);
    }
    Wt[sx * 640 + col] = isTrend ? acc : (wsel[sx] - acc);
}

// ---------------- fold sc_w into ctx cols: Wgin[k=(s,f)][h] ----------------
__global__ void k_compose2(const float* __restrict__ Wt, const float* __restrict__ sc_w,
                           float* __restrict__ Wgin) {
    int n = blockIdx.x * 256 + threadIdx.x;   // 1344*8
    if (n >= KTOT * 8) return;
    int k = n >> 3, h = n & 7;
    int s = k >> 3, f = k & 7;
    float a = 0.f;
    for (int cc = 0; cc < 32; ++cc)
        a = fmaf(sc_w[h * 256 + f * 32 + cc], Wt[s * 640 + 384 + cc * 8 + f], a);
    Wgin[n] = a;
}

// ---------------- build pre-swizzled bf16 B image [5][21][80 col x 64 k] ----------------
// within chunk: byte = (col*128 + koff*2) ^ ((col&7)<<4)   (st-style XOR swizzle)
__global__ void k_img(const float* __restrict__ Wt, const float* __restrict__ Wgin,
                      const float* __restrict__ h0_w, unsigned char* __restrict__ imgb) {
    int idx = blockIdx.x * 256 + threadIdx.x;   // 5*21*80*64 = 537600
    if (idx >= NB * NCHUNK * 80 * 64) return;
    int koff  = idx & 63;
    int rest  = idx >> 6;
    int col   = rest % 80;
    int chunk = rest / 80;        // ct*21 + kc
    int ct    = chunk / NCHUNK;
    int kc    = chunk % NCHUNK;
    int g = ct * 80 + col;
    int k = kc * 64 + koff;
    int s = k >> 3, f = k & 7;
    float val = 0.f;
    if (g < 384) {
        if (f == (g & 7)) val = Wt[s * 640 + g];
    } else if (g < 392) {
        val = Wgin[k * 8 + (g - 384)];
    } else {
        if (f == 7) {
            const int LIDX[11] = {167,166,165,164,163,162,145,144,143,1,0};
            #pragma unroll
            for (int i = 0; i < 11; ++i)
                if (s == LIDX[i]) val = h0_w[(g - 392) * 11 + i];
        }
    }
    int byte = (col * 128 + koff * 2) ^ ((col & 7) << 4);
    *(unsigned short*)(imgb + chunk * CHUNKB + byte) = f2bf(val);
}

// ---------------- MFMA GEMM: Y[16384 x 400] = x[16384 x 1344] * B ----------------
// BM=128, BN=80, BK=64; 4 waves, wave w owns rows [w*32, w*32+32)
__global__ __launch_bounds__(256, 3)
void k_gemm(const float* __restrict__ x, const unsigned char* __restrict__ img,
            float* __restrict__ y, int Btot) {
    __shared__ unsigned char Asb[128 * 128];   // [m][64 k] bf16, XOR-swizzled
    __shared__ unsigned char Bsb[80 * 128];    // [col][64 k] bf16, XOR-swizzled (pre-swizzled img)
    const int t  = threadIdx.x;
    const int b0 = blockIdx.x * 128;
    const int nb = blockIdx.y;
    const int w  = t >> 6, l = t & 63;
    const int lr = l & 15, lg = l >> 4;

    f32x4 acc[2][5];
    #pragma unroll
    for (int i = 0; i < 2; ++i)
        #pragma unroll
        for (int j = 0; j < 5; ++j)
            acc[i][j] = (f32x4){0.f, 0.f, 0.f, 0.f};

    const unsigned char* imgt = img + (size_t)nb * (NCHUNK * CHUNKB);
    const int mrow = t >> 4, kp = t & 15;

    for (int kc = 0; kc < NCHUNK; ++kc) {
        __syncthreads();
        // stage A: 128x64 f32 -> bf16 LDS (swizzled), coalesced 256B row segments
        #pragma unroll
        for (int it = 0; it < 8; ++it) {
            int m  = mrow + it * 16;
            int gr = b0 + m; if (gr >= Btot) gr = Btot - 1;
            const float4 v = *(const float4*)&x[(size_t)gr * KTOT + kc * 64 + kp * 4];
            ushort4 hv;
            hv.x = f2bf(v.x); hv.y = f2bf(v.y); hv.z = f2bf(v.z); hv.w = f2bf(v.w);
            int byte = (m * 128 + kp * 8) ^ ((m & 7) << 4);
            *(ushort4*)&Asb[byte] = hv;
        }
        // stage B: linear 10KB copy (image already swizzled)
        {
            const unsigned char* src = imgt + kc * CHUNKB;
            #pragma unroll
            for (int j2 = 0; j2 < 3; ++j2) {
                int idx = t + j2 * 256;
                if (idx < 640)
                    *(uint4*)&Bsb[idx * 16] = *(const uint4*)&src[idx * 16];
            }
        }
        __syncthreads();
        #pragma unroll
        for (int kk = 0; kk < 2; ++kk) {
            bf16x8 af[2], bfr[5];
            #pragma unroll
            for (int i = 0; i < 2; ++i) {
                int m = w * 32 + i * 16 + lr;
                af[i] = *(const bf16x8*)&Asb[(m * 128 + kk * 64 + lg * 16) ^ ((m & 7) << 4)];
            }
            #pragma unroll
            for (int j = 0; j < 5; ++j) {
                int c = j * 16 + lr;
                bfr[j] = *(const bf16x8*)&Bsb[(c * 128 + kk * 64 + lg * 16) ^ ((c & 7) << 4)];
            }
            #pragma unroll
            for (int i = 0; i < 2; ++i)
                #pragma unroll
                for (int j = 0; j < 5; ++j)
                    acc[i][j] = __builtin_amdgcn_mfma_f32_16x16x32_bf16(af[i], bfr[j], acc[i][j], 0, 0, 0);
        }
    }
    // epilogue: D row = (l>>4)*4 + reg, col = l&15  [m89-verified layout]
    #pragma unroll
    for (int i = 0; i < 2; ++i)
        #pragma unroll
        for (int j = 0; j < 5; ++j)
            #pragma unroll
            for (int reg = 0; reg < 4; ++reg) {
                int row = b0 + w * 32 + i * 16 + lg * 4 + reg;
                int col = nb * 80 + j * 16 + lr;
                if (row < Btot) y[(size_t)row * NOUT + col] = acc[i][j][reg];
            }
}

// ---------------- VQC: 16 lanes hold the 16 complex amplitudes (verified) ----------------
__device__ __forceinline__ float shflg(float v, int grp, int idx) {
    return __shfl(v, grp + idx, 64);
}

__device__ void vqc_run(const float cq[4], const float sq[4],
                        const float* __restrict__ rc,
                        int l, int grp, float exps[4]) {
    float re = (l == 0) ? 1.f : 0.f;
    float im = 0.f;
    #pragma unroll
    for (int layer = 0; layer < 2; ++layer) {
        #pragma unroll
        for (int q = 0; q < 4; ++q) {
            int m = 1 << (3 - q);
            float pre = shflg(re, grp, l ^ m);
            float pim = shflg(im, grp, l ^ m);
            float sg = (l & m) ? sq[q] : -sq[q];
            re = cq[q] * re + sg * pre;
            im = cq[q] * im + sg * pim;
        }
        #pragma unroll
        for (int q = 0; q < 4; ++q) {
            int m = 1 << (3 - q);
            const float* g = rc + (layer * 4 + q) * 4;
            float A = g[0], B = g[1], C = g[2], D = g[3];
            float pre = shflg(re, grp, l ^ m);
            float pim = shflg(im, grp, l ^ m);
            float car, cai, cpr, cpi;
            if (l & m) { car = A; cai = -B; cpr =  C; cpi = -D; }
            else       { car = A; cai =  B; cpr = -C; cpi = -D; }
            float nre = car * re - cai * im + cpr * pre - cpi * pim;
            float nim = car * im + cai * re + cpr * pim + cpi * pre;
            re = nre; im = nim;
        }
        #pragma unroll
        for (int q = 0; q < 4; ++q) {
            int mc = 1 << (3 - q);
            int mt = 1 << (3 - ((q + 1) & 3));
            float pre = shflg(re, grp, l ^ mt);
            float pim = shflg(im, grp, l ^ mt);
            if (l & mc) { re = pre; im = pim; }
        }
    }
    float prob = re * re + im * im;
    float v0 = (l & 8) ? -prob : prob;
    float v1 = (l & 4) ? -prob : prob;
    float v2 = (l & 2) ? -prob : prob;
    float v3 = (l & 1) ? -prob : prob;
    #pragma unroll
    for (int m = 1; m < 16; m <<= 1) {
        v0 += __shfl_xor(v0, m, 64);
        v1 += __shfl_xor(v1, m, 64);
        v2 += __shfl_xor(v2, m, 64);
        v3 += __shfl_xor(v3, m, 64);
    }
    exps[0] = v0; exps[1] = v1; exps[2] = v2; exps[3] = v3;
}

// ---------------- post: VQC chain + fuse, 16 rows/block ----------------
__global__ __launch_bounds__(256)
void k_post(const float* __restrict__ y, const float* __restrict__ rotc,
            const float* __restrict__ cgin, const float* __restrict__ h0_b,
            const float* __restrict__ crz_w, const float* __restrict__ crz_b,
            const float* __restrict__ cn_w, const float* __restrict__ cn_b,
            const float* __restrict__ expand_w, const float* __restrict__ expand_b,
            const float* __restrict__ mod_w, const float* __restrict__ mod_b,
            const float* __restrict__ trend_b, const float* __restrict__ seasonal_b,
            const float* __restrict__ fusion_alpha,
            float* __restrict__ out, int Btot) {
    __shared__ float modt[16 * PRED];
    const int t    = threadIdx.x;
    const int b0   = blockIdx.x * 16;
    const int l    = t & 15;
    const int lane = t & 63;
    const int grp  = lane & 48;
    const int r    = t >> 4;
    int row = b0 + r; if (row >= Btot) row = Btot - 1;
    const float* yr = y + (size_t)row * NOUT;

    float4 g0 = *(const float4*)&yr[384];
    float4 g1 = *(const float4*)&yr[388];
    float4 q0 = *(const float4*)&yr[392];
    float4 q1 = *(const float4*)&yr[396];
    float gpre[8] = {g0.x, g0.y, g0.z, g0.w, g1.x, g1.y, g1.z, g1.w};
    float hpre[8] = {q0.x, q0.y, q0.z, q0.w, q1.x, q1.y, q1.z, q1.w};
    float gin[HID], h0v[HID];
    #pragma unroll
    for (int h = 0; h < HID; ++h) {
        gin[h] = ftanh(gpre[h] + cgin[h]);
        h0v[h] = ftanh(hpre[h] + h0_b[h]);
    }

    float rz[4];
    #pragma unroll
    for (int q = 0; q < 4; ++q) {
        float a = crz_b[q];
        #pragma unroll
        for (int k = 0; k < 8; ++k) a = fmaf(gin[k], crz_w[q * 16 + k], a);
        #pragma unroll
        for (int k = 0; k < 8; ++k) a = fmaf(h0v[k], crz_w[q * 16 + 8 + k], a);
        rz[q] = ftanh(a) * PI_F;
    }
    float cq[4], sq[4];
    #pragma unroll
    for (int q = 0; q < 4; ++q) { cq[q] = __cosf(0.5f * rz[q]); sq[q] = __sinf(0.5f * rz[q]); }

    float er[4], ez[4];
    vqc_run(cq, sq, rotc + 0 * 32, l, grp, er);
    vqc_run(cq, sq, rotc + 1 * 32, l, grp, ez);

    float rr[HID], zz[HID];
    #pragma unroll
    for (int h = 0; h < HID; ++h) {
        float a = expand_b[h], b = expand_b[h];
        #pragma unroll
        for (int q = 0; q < 4; ++q) {
            a = fmaf(er[q], expand_w[h * 4 + q], a);
            b = fmaf(ez[q], expand_w[h * 4 + q], b);
        }
        rr[h] = sigm(a);
        zz[h] = sigm(b);
    }

    float ni[4];
    #pragma unroll
    for (int q = 0; q < 4; ++q) {
        float a = cn_b[q];
        #pragma unroll
        for (int k = 0; k < 8; ++k) a = fmaf(rr[k] * h0v[k], cn_w[q * 16 + k], a);
        #pragma unroll
        for (int k = 0; k < 8; ++k) a = fmaf(gin[k], cn_w[q * 16 + 8 + k], a);
        ni[q] = ftanh(a) * PI_F;
    }
    #pragma unroll
    for (int q = 0; q < 4; ++q) { cq[q] = __cosf(0.5f * ni[q]); sq[q] = __sinf(0.5f * ni[q]); }
    float en[4];
    vqc_run(cq, sq, rotc + 2 * 32, l, grp, en);

    float hn[HID];
    #pragma unroll
    for (int h = 0; h < HID; ++h) {
        float a = expand_b[h];
        #pragma unroll
        for (int q = 0; q < 4; ++q) a = fmaf(en[q], expand_w[h * 4 + q], a);
        float nn = ftanh(a);
        hn[h] = (1.f - zz[h]) * nn + zz[h] * h0v[h];
    }

    {
        int p = l;
        float a = mod_b[p];
        #pragma unroll
        for (int h = 0; h < HID; ++h) a = fmaf(hn[h], mod_w[p * 8 + h], a);
        modt[r * PRED + p] = ftanh(a);
        if (l < 8) {
            p = l + 16;
            a = mod_b[p];
            #pragma unroll
            for (int h = 0; h < HID; ++h) a = fmaf(hn[h], mod_w[p * 8 + h], a);
            modt[r * PRED + p] = ftanh(a);
        }
    }
    __syncthreads();

    const float alpha = sigm(fusion_alpha[0]);
    #pragma unroll
    for (int u = 0; u < 3; ++u) {
        int idx = t + u * 256;            // float4 units, 768 total = 16 rows * 48
        int r2  = idx / 48;
        int pfu = (idx % 48) * 4;
        int row2 = b0 + r2;
        if (row2 < Btot) {
            const float* yr2 = y + (size_t)row2 * NOUT;
            float4 yt = *(const float4*)&yr2[pfu];
            float4 ys = *(const float4*)&yr2[192 + pfu];
            int p = pfu >> 3;
            float md = modt[r2 * PRED + p];
            float tb = trend_b[p], sb = seasonal_b[p];
            float s1 = alpha * (1.f + md), s0 = 1.f - alpha;
            float4 o;
            o.x = s1 * (ys.x + sb) + s0 * (yt.x + tb);
            o.y = s1 * (ys.y + sb) + s0 * (yt.y + tb);
            o.z = s1 * (ys.z + sb) + s0 * (yt.z + tb);
            o.w = s1 * (ys.w + sb) + s0 * (yt.w + tb);
            *(float4*)&out[(size_t)row2 * 192 + pfu] = o;
        }
    }
}

extern "C" void kernel_launch(void* const* d_in, const int* in_sizes, int n_in,
                              void* d_out, int out_size, void* d_ws, size_t ws_size,
                              hipStream_t stream) {
    const float* x          = (const float*)d_in[0];
    const float* decomp_w   = (const float*)d_in[1];
    const float* trend_w    = (const float*)d_in[2];
    const float* trend_b    = (const float*)d_in[3];
    const float* seasonal_w = (const float*)d_in[4];
    const float* seasonal_b = (const float*)d_in[5];
    const float* h0_w       = (const float*)d_in[6];
    const float* h0_b       = (const float*)d_in[7];
    const float* ta_w       = (const float*)d_in[8];
    const float* ta_b       = (const float*)d_in[9];
    const float* sc_w       = (const float*)d_in[10];
    const float* sc_b       = (const float*)d_in[11];
    const float* crz_w      = (const float*)d_in[12];
    const float* crz_b      = (const float*)d_in[13];
    const float* cn_w       = (const float*)d_in[14];
    const float* cn_b       = (const float*)d_in[15];
    const float* vqc_r      = (const float*)d_in[16];
    const float* vqc_u      = (const float*)d_in[17];
    const float* vqc_c      = (const float*)d_in[18];
    const float* expand_w   = (const float*)d_in[19];
    const float* expand_b   = (const float*)d_in[20];
    const float* mod_w      = (const float*)d_in[21];
    const float* mod_b      = (const float*)d_in[22];
    const float* fus_a      = (const float*)d_in[23];
    float* out = (float*)d_out;

    float* ws   = (float*)d_ws;
    float* dw   = ws + WS_DW;
    float* rotc = ws + WS_ROTC;
    float* cgin = ws + WS_CGIN;
    float* Wt   = ws + WS_WT;
    float* Wgin = ws + WS_WGIN;
    float* y    = ws + WS_Y;
    unsigned char* img = (unsigned char*)d_ws + WS_IMG_BYTE;

    const int Btot = in_sizes[0] / (SEQ * NF);

    k_setup<<<1, 256, 0, stream>>>(decomp_w, vqc_r, vqc_u, vqc_c, sc_w, sc_b, ta_b,
                                   dw, rotc, cgin);
    k_compose<<<(SEQ * 640 + 255) / 256, 256, 0, stream>>>(dw, trend_w, seasonal_w, ta_w, Wt);
    k_compose2<<<(KTOT * 8 + 255) / 256, 256, 0, stream>>>(Wt, sc_w, Wgin);
    k_img<<<(NB * NCHUNK * 80 * 64 + 255) / 256, 256, 0, stream>>>(Wt, Wgin, h0_w, img);

    dim3 ggrid((Btot + 127) / 128, NB);
    k_gemm<<<ggrid, 256, 0, stream>>>(x, img, y, Btot);

    k_post<<<(Btot + 15) / 16, 256, 0, stream>>>(y, rotc, cgin, h0_b,
                                                 crz_w, crz_b, cn_w, cn_b,
                                                 expand_w, expand_b, mod_w, mod_b,
                                                 trend_b, seasonal_b, fus_a, out, Btot);
}